// Round 8
// baseline (122.040 us; speedup 1.0000x reference)
//
#include <hip/hip_runtime.h>
#include <math.h>

#define BATCH 65536
#define DT_C 0.0166667f
#define NN_RATIO_C 0.3f

// ---- d_ws packed-weight layout (uint32 element indices) ----
#define OFF_W2 0        // [m][t][lane] x uint4 : 8*2*64*4 = 4096 uints
#define OFF_W3 4096     // same                  : 4096
#define OFF_W1 8192     // [m][quad*8+j] x uint2 : 8*32*2 = 512  (A=pk2(w0,w1), B=pk2(w2,bias))
#define OFF_B2 8704     // [m][d] pk2 pairs      : 128
#define OFF_B3 8832     // 128
#define OFF_W4 8960     // 128

typedef __bf16 bf16x8 __attribute__((ext_vector_type(8)));
typedef __bf16 bf16x2 __attribute__((ext_vector_type(2)));
typedef unsigned short us8 __attribute__((ext_vector_type(8)));
typedef float f32x4 __attribute__((ext_vector_type(4)));

union FragU { us8 u; bf16x8 b; unsigned d[4]; uint4 q; };
union PairU { unsigned u; bf16x2 v; };

__device__ __forceinline__ unsigned short f2bf(float f) {
    union { __bf16 h; unsigned short u; } v;
    v.h = (__bf16)f;                        // hardware RTNE cvt
    return v.u;
}
__device__ __forceinline__ unsigned pk2(float lo, float hi) {
    return (unsigned)f2bf(lo) | ((unsigned)f2bf(hi) << 16);
}
__device__ __forceinline__ float up_lo(unsigned u) { return __uint_as_float(u << 16); }
__device__ __forceinline__ float up_hi(unsigned u) { return __uint_as_float(u & 0xFFFF0000u); }
__device__ __forceinline__ float lrelu(float x) { return fmaxf(x, 0.01f * x); }

__device__ __forceinline__ float dot2bf(unsigned pa, unsigned pb, float c) {
#if __has_builtin(__builtin_amdgcn_fdot2_f32_bf16)
    PairU ua, ub; ua.u = pa; ub.u = pb;
    return __builtin_amdgcn_fdot2_f32_bf16(ua.v, ub.v, c, false);
#else
    return up_lo(pa) * up_lo(pb) + (up_hi(pa) * up_hi(pb) + c);
#endif
}

// ---- pack kernel: fragment-ordered bf16 weights into d_ws (runs every call) ----
__global__ __launch_bounds__(512) void pack_kernel(
    const float* __restrict__ W1, const float* __restrict__ b1,
    const float* __restrict__ W2, const float* __restrict__ W3,
    const float* __restrict__ b2, const float* __restrict__ b3,
    const float* __restrict__ W4, unsigned* __restrict__ wsp)
{
    const int m   = blockIdx.x;      // one block per muscle
    const int tid = threadIdx.x;
    if (tid < 256) {                 // W2 / W3 MFMA A-fragments
        const int which = tid >> 7;
        const int t     = (tid >> 6) & 1;
        const int lane  = tid & 63;
        const int o     = t * 16 + (lane & 15);
        const int k     = (lane >> 4) * 8;
        const float* src = (which ? W3 : W2) + m * 1024 + o * 32 + k;
        uint4 v;
        v.x = pk2(src[0], src[1]);
        v.y = pk2(src[2], src[3]);
        v.z = pk2(src[4], src[5]);
        v.w = pk2(src[6], src[7]);
        ((uint4*)(wsp + (which ? OFF_W3 : OFF_W2)))[(m * 2 + t) * 64 + lane] = v;
    } else if (tid < 288) {          // W1 dot2 pairs (+ b1 folded)
        const int o = tid - 256;     // o = quad*8 + j
        const float* p1 = W1 + m * 96 + o * 3;
        wsp[OFF_W1 + (m * 32 + o) * 2]     = pk2(p1[0], p1[1]);
        wsp[OFF_W1 + (m * 32 + o) * 2 + 1] = pk2(p1[2], b1[m * 32 + o]);
    } else if (tid < 304) {
        const int d = tid - 288;
        wsp[OFF_B2 + m * 16 + d] = pk2(b2[m * 32 + 2 * d], b2[m * 32 + 2 * d + 1]);
    } else if (tid < 320) {
        const int d = tid - 304;
        wsp[OFF_B3 + m * 16 + d] = pk2(b3[m * 32 + 2 * d], b3[m * 32 + 2 * d + 1]);
    } else if (tid < 336) {
        const int d = tid - 320;
        wsp[OFF_W4 + m * 16 + d] = pk2(W4[m * 32 + 2 * d], W4[m * 32 + 2 * d + 1]);
    }
}

// Block = 512 threads = 8 waves; wave w == muscle w; 64 rows/block, 1024 blocks.
// Register-lean rebuild targeting 8 waves/SIMD (4 blocks/CU = 2048 thr = max):
//  - weights pre-packed by pack_kernel; W1/b2/b3 tables read from LDS (3 KB),
//    only w2f/w3f frags (16 regs) + packed w4 (4) persist in registers.
//  - single stream, in-loop shfl_xor quad-reduction (R3-proven), no prefetch.
// Kept (verified R3-R7): MFMA D[o][b]=sum_i W[o][i]*X[b][i]; Xbuf stride-40
// transpose (<=2-way bank aliasing = free); bf16 biases (R5-proven); 3x3 expm.
__global__ __launch_bounds__(512, 8) void joint_kernel(
    const float* __restrict__ SS, const float* __restrict__ Alphas,
    const float* __restrict__ K0s, const float* __restrict__ K1s,
    const float* __restrict__ L0s, const float* __restrict__ L1s,
    const float* __restrict__ Ms, const float* __restrict__ Ivec,
    const float* __restrict__ Bv, const float* __restrict__ Kv,
    const float* __restrict__ b4, const unsigned* __restrict__ wsp,
    float* __restrict__ out)
{
    __shared__ unsigned wtab[768];            // w1:0..511, b2:512..639, b3:640..767
    __shared__ unsigned short Xbuf[8][640];   // per-wave 16x40 transpose tile
    __shared__ float red_k[8][64];
    __shared__ float red_bf[8][64];

    const int tid  = threadIdx.x;
    const int lane = tid & 63;
    const int w    = tid >> 6;
    const int m    = __builtin_amdgcn_readfirstlane(w);
    const int n16  = lane & 15;
    const int quad = lane >> 4;

    // wave-uniform scalars -> SGPRs
    const float ms = Ms[m];
    const float k0 = K0s[m], k1 = K1s[m], l0 = L0s[m], l1 = L1s[m];
    const float b4m = b4[m];

    // cooperative copy of small tables (w1 pairs + b2 + b3) to LDS
    #pragma unroll
    for (int i = 0; i < 2; ++i) {
        const int idx = tid + i * 512;
        if (idx < 768) wtab[idx] = wsp[OFF_W1 + idx];
    }

    // W2/W3 fragments: one uint4 load each per tile
    FragU w2f[2], w3f[2];
    #pragma unroll
    for (int t = 0; t < 2; ++t) {
        w2f[t].q = ((const uint4*)(wsp + OFF_W2))[(m * 2 + t) * 64 + lane];
        w3f[t].q = ((const uint4*)(wsp + OFF_W3))[(m * 2 + t) * 64 + lane];
    }
    // packed w4 (kept as 4 regs, unpacked per use)
    const unsigned* pw4 = wsp + OFF_W4 + m * 16;
    const uint2 w4a = *(const uint2*)(pw4 + quad * 2);
    const uint2 w4b = *(const uint2*)(pw4 + 8 + quad * 2);

    __syncthreads();   // wtab ready

    unsigned short* const X = &Xbuf[w][0];
    const unsigned* const wt1 = &wtab[(m * 4 + quad) * 16];
    const unsigned* const bt2 = &wtab[512 + m * 16 + quad * 2];
    const unsigned* const bt3 = &wtab[640 + m * 16 + quad * 2];
    const int rowbase = blockIdx.x * 64;

    #pragma unroll 1
    for (int s = 0; s < 4; ++s) {
        const int row = s * 16 + n16;
        const int bb  = rowbase + row;
        const float2 ssv = *(const float2*)&SS[2 * bb];
        float a = Alphas[8 * bb + m];
        a = fminf(fmaxf(a, 0.0f), 1.0f);
        const float l  = ssv.x * ms;
        const float dl = ssv.y * ms;

        // ---- layer 1: dot2 pairs from LDS, result directly in B-frag layout ----
        const unsigned pldl = pk2(l, dl);
        const unsigned pa1  = pk2(a, 1.0f);
        const uint4 q0 = *(const uint4*)&wt1[0];
        const uint4 q1 = *(const uint4*)&wt1[4];
        const uint4 q2 = *(const uint4*)&wt1[8];
        const uint4 q3 = *(const uint4*)&wt1[12];
        float hv[8];
        hv[0] = lrelu(dot2bf(q0.x, pldl, dot2bf(q0.y, pa1, 0.0f)));
        hv[1] = lrelu(dot2bf(q0.z, pldl, dot2bf(q0.w, pa1, 0.0f)));
        hv[2] = lrelu(dot2bf(q1.x, pldl, dot2bf(q1.y, pa1, 0.0f)));
        hv[3] = lrelu(dot2bf(q1.z, pldl, dot2bf(q1.w, pa1, 0.0f)));
        hv[4] = lrelu(dot2bf(q2.x, pldl, dot2bf(q2.y, pa1, 0.0f)));
        hv[5] = lrelu(dot2bf(q2.z, pldl, dot2bf(q2.w, pa1, 0.0f)));
        hv[6] = lrelu(dot2bf(q3.x, pldl, dot2bf(q3.y, pa1, 0.0f)));
        hv[7] = lrelu(dot2bf(q3.z, pldl, dot2bf(q3.w, pa1, 0.0f)));
        FragU h1;
        h1.d[0] = pk2(hv[0], hv[1]); h1.d[1] = pk2(hv[2], hv[3]);
        h1.d[2] = pk2(hv[4], hv[5]); h1.d[3] = pk2(hv[6], hv[7]);

        // ---- layer 2 (MFMA), bias from LDS ----
        const uint2 cb = *(const uint2*)bt2;
        const uint2 ch = *(const uint2*)(bt2 + 8);
        f32x4 c0, c1;
        c0[0] = up_lo(cb.x); c0[1] = up_hi(cb.x); c0[2] = up_lo(cb.y); c0[3] = up_hi(cb.y);
        c1[0] = up_lo(ch.x); c1[1] = up_hi(ch.x); c1[2] = up_lo(ch.y); c1[3] = up_hi(ch.y);
        f32x4 acc0 = __builtin_amdgcn_mfma_f32_16x16x32_bf16(w2f[0].b, h1.b, c0, 0, 0, 0);
        f32x4 acc1 = __builtin_amdgcn_mfma_f32_16x16x32_bf16(w2f[1].b, h1.b, c1, 0, 0, 0);

        // ---- transpose via LDS (same-wave in-order DS, no explicit wait) ----
        uint2 st0, st1;
        st0.x = pk2(lrelu(acc0[0]), lrelu(acc0[1]));
        st0.y = pk2(lrelu(acc0[2]), lrelu(acc0[3]));
        st1.x = pk2(lrelu(acc1[0]), lrelu(acc1[1]));
        st1.y = pk2(lrelu(acc1[2]), lrelu(acc1[3]));
        *(uint2*)&X[n16 * 40 + quad * 4]      = st0;   // rows o=quad*4+r
        *(uint2*)&X[n16 * 40 + 16 + quad * 4] = st1;   // rows o=16+quad*4+r
        FragU hf;
        hf.u = *(const us8*)&X[n16 * 40 + quad * 8];   // row n16, k=quad*8+j

        // ---- layer 3 (MFMA), bias from LDS ----
        const uint2 db = *(const uint2*)bt3;
        const uint2 dh = *(const uint2*)(bt3 + 8);
        c0[0] = up_lo(db.x); c0[1] = up_hi(db.x); c0[2] = up_lo(db.y); c0[3] = up_hi(db.y);
        c1[0] = up_lo(dh.x); c1[1] = up_hi(dh.x); c1[2] = up_lo(dh.y); c1[3] = up_hi(dh.y);
        acc0 = __builtin_amdgcn_mfma_f32_16x16x32_bf16(w3f[0].b, hf.b, c0, 0, 0, 0);
        acc1 = __builtin_amdgcn_mfma_f32_16x16x32_bf16(w3f[1].b, hf.b, c1, 0, 0, 0);

        // ---- layer 4: per-quad partial dot + butterfly over quads ----
        float d = lrelu(acc0[0]) * up_lo(w4a.x) + lrelu(acc0[1]) * up_hi(w4a.x)
                + lrelu(acc0[2]) * up_lo(w4a.y) + lrelu(acc0[3]) * up_hi(w4a.y)
                + lrelu(acc1[0]) * up_lo(w4b.x) + lrelu(acc1[1]) * up_hi(w4b.x)
                + lrelu(acc1[2]) * up_lo(w4b.y) + lrelu(acc1[3]) * up_hi(w4b.y);
        d += __shfl_xor(d, 16, 64);
        d += __shfl_xor(d, 32, 64);

        if (lane < 16) {   // quad 0 holds the full dot for row
            const float e2x = __expf(2.0f * (d + b4m));
            const float nn = (1.0f - 2.0f / (e2x + 1.0f)) * NN_RATIO_C;
            const float kk = k0 + k1 * a;
            red_k[w][row]  = kk * ms * ms;
            red_bf[w][row] = (kk * (l0 + l1 * a - fabsf(l)) + k1 * l1 * a * a * nn) * ms;
        }
    }

    __syncthreads();

    if (tid < 64) {
        float Ksum = 0.0f, BFsum = 0.0f;
        #pragma unroll
        for (int mm = 0; mm < 8; ++mm) {
            Ksum  += red_k[mm][tid];
            BFsum += red_bf[mm][tid];
        }

        const int b = rowbase + tid;
        const float2 ssv = *(const float2*)&SS[2 * b];
        const float s0 = ssv.x, s1 = ssv.y;
        const float I  = Ivec[0];
        const float bv = Bv[0];
        const float kv = Kv[0];
        const float inv_I = 1.0f / I;

        const float A10 = -(Ksum + kv) * inv_I;
        const float D   = 2.0f * sqrtf(Ksum * I);
        const float A11 = -(D + bv) * inv_I;
        const float B10 = BFsum * inv_I;

        // Reduced 3x3 expm (verified R1-R7)
        const float m01 = DT_C;
        const float m10 = A10 * DT_C, m11 = A11 * DT_C, m12 = B10 * DT_C;

        float p00 = 0.0f, p01 = m01, p02 = 0.0f;
        float p10 = m10,  p11 = m11, p12 = m12;
        float t00 = p00, t01 = p01, t02 = p02;
        float t10 = p10, t11 = p11, t12 = p12;
        #pragma unroll
        for (int k = 2; k <= 16; ++k) {
            float inv = 1.0f / (float)k;
            float q00 = (p01 * m10) * inv;
            float q01 = (p00 * m01 + p01 * m11) * inv;
            float q02 = (p01 * m12) * inv;
            float q10 = (p11 * m10) * inv;
            float q11 = (p10 * m01 + p11 * m11) * inv;
            float q12 = (p11 * m12) * inv;
            p00 = q00; p01 = q01; p02 = q02;
            p10 = q10; p11 = q11; p12 = q12;
            t00 += p00; t01 += p01; t02 += p02;
            t10 += p10; t11 += p11; t12 += p12;
        }
        const float E00 = 1.0f + t00, E01 = t01, c0 = t02;
        const float E10 = t10,        E11 = 1.0f + t11, c1 = t12;

        const float o0 = E00 * s0 + E01 * s1 + c0;
        const float o1 = E10 * s0 + E11 * s1 + c1;

        out[b] = o0;                               // output 0: SSout[:,0:1]
        float2 o12; o12.x = o0; o12.y = o1;        // output 1: SSout[:,:,0]
        *(float2*)&out[BATCH + 2 * b] = o12;
    }
}

extern "C" void kernel_launch(void* const* d_in, const int* in_sizes, int n_in,
                              void* d_out, int out_size, void* d_ws, size_t ws_size,
                              hipStream_t stream) {
    const float* SS     = (const float*)d_in[0];
    const float* Alphas = (const float*)d_in[1];
    const float* K0s    = (const float*)d_in[2];
    const float* K1s    = (const float*)d_in[3];
    const float* L0s    = (const float*)d_in[4];
    const float* L1s    = (const float*)d_in[5];
    const float* Ms     = (const float*)d_in[6];
    const float* I      = (const float*)d_in[7];
    const float* Bv     = (const float*)d_in[8];
    const float* Kv     = (const float*)d_in[9];
    const float* W1     = (const float*)d_in[10];
    const float* b1     = (const float*)d_in[11];
    const float* W2     = (const float*)d_in[12];
    const float* b2     = (const float*)d_in[13];
    const float* W3     = (const float*)d_in[14];
    const float* b3     = (const float*)d_in[15];
    const float* W4     = (const float*)d_in[16];
    const float* b4     = (const float*)d_in[17];
    unsigned* wsp = (unsigned*)d_ws;
    float* out = (float*)d_out;

    pack_kernel<<<8, 512, 0, stream>>>(W1, b1, W2, W3, b2, b3, W4, wsp);
    joint_kernel<<<BATCH / 64, 512, 0, stream>>>(
        SS, Alphas, K0s, K1s, L0s, L1s, Ms, I, Bv, Kv, b4, wsp, out);
}

// Round 9
// 106.799 us; speedup vs baseline: 1.1427x; 1.1427x over previous
//
#include <hip/hip_runtime.h>
#include <math.h>

#define BATCH 65536
#define DT_C 0.0166667f
#define NN_RATIO_C 0.3f

typedef __bf16 bf16x8 __attribute__((ext_vector_type(8)));
typedef __bf16 bf16x2 __attribute__((ext_vector_type(2)));
typedef float f32x4 __attribute__((ext_vector_type(4)));
typedef float f32x16 __attribute__((ext_vector_type(16)));

union Frag8 { unsigned d[4]; bf16x8 b; };
union PairU { unsigned u; bf16x2 v; };

__device__ __forceinline__ unsigned short f2bf(float f) {
    union { __bf16 h; unsigned short u; } v;
    v.h = (__bf16)f;                        // hardware RTNE cvt
    return v.u;
}
__device__ __forceinline__ unsigned pk2(float lo, float hi) {
    return (unsigned)f2bf(lo) | ((unsigned)f2bf(hi) << 16);
}
__device__ __forceinline__ float up_lo(unsigned u) { return __uint_as_float(u << 16); }
__device__ __forceinline__ float up_hi(unsigned u) { return __uint_as_float(u & 0xFFFF0000u); }
__device__ __forceinline__ float lrelu(float x) { return fmaxf(x, 0.01f * x); }

__device__ __forceinline__ float dot2bf(unsigned pa, unsigned pb, float c) {
#if __has_builtin(__builtin_amdgcn_fdot2_f32_bf16)
    PairU ua, ub; ua.u = pa; ub.u = pb;
    return __builtin_amdgcn_fdot2_f32_bf16(ua.v, ub.v, c, false);
#else
    return up_lo(pa) * up_lo(pb) + (up_hi(pa) * up_hi(pb) + c);
#endif
}

// Block = 512 = 8 waves; wave w == muscle w; 64 rows/block, 1024 blocks.
// 32x32x16 restructure (R8 post-mortem: 16x16 structure pinned at ~24us over
// 3 rounds; this halves MFMAs/VALU/cross-lane ops per row and removes ALL
// LDS round trips from the MLP):
//   mfma_f32_32x32x16_bf16: A[m=lane&31][k=h*8+j] (h=lane>>5), B likewise,
//   D: col=lane&31, row=(reg&3)+8*(reg>>2)+4*h  [C/D verified m74/m101].
//   Layer 1: ONE MFMA, bias folded as 4th input col (A[k][3]=b1, B[b][3]=1).
//   Inter-layer transpose: lane (b,h) holds D rows {8g+r+4h}; B-frag chunk c
//   needs k=16c+8h+j. Index algebra 8g+4H+2rp = 16c+8h+2jp gives: own dwords
//   g=2c+h plus partner's dwords g=2c+h -> 4x shfl_xor(32) + cndmask, no LDS.
// Kept verified: 3x3-expm epilogue (R1-R8), bf16 numerics (absmax ~2e-3),
// deferred cross-muscle reduction via 4KB LDS. Pack kernel dropped (R8 showed
// it added serialized overhead).
__global__ __launch_bounds__(512, 4) void joint_kernel(
    const float* __restrict__ SS, const float* __restrict__ Alphas,
    const float* __restrict__ K0s, const float* __restrict__ K1s,
    const float* __restrict__ L0s, const float* __restrict__ L1s,
    const float* __restrict__ Ms, const float* __restrict__ Ivec,
    const float* __restrict__ Bv, const float* __restrict__ Kv,
    const float* __restrict__ W1, const float* __restrict__ b1,
    const float* __restrict__ W2, const float* __restrict__ b2,
    const float* __restrict__ W3, const float* __restrict__ b3,
    const float* __restrict__ W4, const float* __restrict__ b4,
    float* __restrict__ out)
{
    __shared__ float red_k[8][64];
    __shared__ float red_bf[8][64];

    const int tid  = threadIdx.x;
    const int lane = tid & 63;
    const int w    = tid >> 6;
    const int m    = __builtin_amdgcn_readfirstlane(w);
    const int n32  = lane & 31;
    const int h    = lane >> 5;
    const bool h0  = (h == 0);

    // wave-uniform scalars -> SGPRs
    const float ms = Ms[m];
    const float k0 = K0s[m], k1 = K1s[m], l0 = L0s[m], l1 = L1s[m];
    const float b4m = b4[m];

    // ---- layer-1 A-fragment: W1[k=n32][c0..c2] + bias as 4th column ----
    Frag8 w1f;
    {
        const float* p1 = W1 + m * 96 + n32 * 3;
        const float bb  = b1[m * 32 + n32];
        w1f.d[0] = h0 ? pk2(p1[0], p1[1]) : 0u;
        w1f.d[1] = h0 ? pk2(p1[2], bb)    : 0u;
        w1f.d[2] = 0u; w1f.d[3] = 0u;
    }

    // ---- W2/W3 A-fragments, two K=16 chunks each ----
    Frag8 w2f[2], w3f[2];
    #pragma unroll
    for (int c = 0; c < 2; ++c) {
        const float* p2 = W2 + m * 1024 + n32 * 32 + c * 16 + h * 8;
        const float* p3 = W3 + m * 1024 + n32 * 32 + c * 16 + h * 8;
        f32x4 a2 = *(const f32x4*)p2, q2 = *(const f32x4*)(p2 + 4);
        f32x4 a3 = *(const f32x4*)p3, q3 = *(const f32x4*)(p3 + 4);
        w2f[c].d[0] = pk2(a2[0], a2[1]); w2f[c].d[1] = pk2(a2[2], a2[3]);
        w2f[c].d[2] = pk2(q2[0], q2[1]); w2f[c].d[3] = pk2(q2[2], q2[3]);
        w3f[c].d[0] = pk2(a3[0], a3[1]); w3f[c].d[1] = pk2(a3[2], a3[3]);
        w3f[c].d[2] = pk2(q3[0], q3[1]); w3f[c].d[3] = pk2(q3[2], q3[3]);
    }

    // ---- w4 / b2 / b3 packed in D-row order: dword d -> rows (o, o+1),
    //      o = 8*(d>>1) + 4h + 2*(d&1)  (addresses uniform over 32 lanes) ----
    unsigned w4d[8], b2d[8], b3d[8];
    #pragma unroll
    for (int d = 0; d < 8; ++d) {
        const int o = 8 * (d >> 1) + 4 * h + 2 * (d & 1);
        w4d[d] = pk2(W4[m * 32 + o], W4[m * 32 + o + 1]);
        b2d[d] = pk2(b2[m * 32 + o], b2[m * 32 + o + 1]);
        b3d[d] = pk2(b3[m * 32 + o], b3[m * 32 + o + 1]);
    }

    const int rowbase = blockIdx.x * 64;
    f32x16 z16;
    #pragma unroll
    for (int i = 0; i < 16; ++i) z16[i] = 0.0f;

    #pragma unroll
    for (int it = 0; it < 2; ++it) {
        const int row = it * 32 + n32;
        const int bb  = rowbase + row;
        const float2 ssv = *(const float2*)&SS[2 * bb];
        float a = Alphas[8 * bb + m];
        a = fminf(fmaxf(a, 0.0f), 1.0f);
        const float l  = ssv.x * ms;
        const float dl = ssv.y * ms;

        // ---- layer 1: one MFMA (inputs in cols 0..3 of K=16) ----
        Frag8 x1;
        x1.d[0] = h0 ? pk2(l, dl)   : 0u;
        x1.d[1] = h0 ? pk2(a, 1.0f) : 0u;
        x1.d[2] = 0u; x1.d[3] = 0u;
        f32x16 D = __builtin_amdgcn_mfma_f32_32x32x16_bf16(w1f.b, x1.b, z16, 0, 0, 0);

        // lrelu + pack into row-pair dwords od[d] = rows (8g+4h+2rp, +1)
        unsigned od[8];
        #pragma unroll
        for (int d = 0; d < 8; ++d) {
            const int r0 = 4 * (d >> 1) + 2 * (d & 1);
            od[d] = pk2(lrelu(D[r0]), lrelu(D[r0 + 1]));
        }

        // ---- half-exchange #1: D-rows -> B-frag chunks ----
        Frag8 Bc[2];
        {
            unsigned rc0 = __shfl_xor(h0 ? od[2] : od[0], 32, 64);
            unsigned rc1 = __shfl_xor(h0 ? od[3] : od[1], 32, 64);
            unsigned rc2 = __shfl_xor(h0 ? od[6] : od[4], 32, 64);
            unsigned rc3 = __shfl_xor(h0 ? od[7] : od[5], 32, 64);
            Bc[0].d[0] = h0 ? od[0] : rc0;  Bc[0].d[1] = h0 ? od[1] : rc1;
            Bc[0].d[2] = h0 ? rc0 : od[2];  Bc[0].d[3] = h0 ? rc1 : od[3];
            Bc[1].d[0] = h0 ? od[4] : rc2;  Bc[1].d[1] = h0 ? od[5] : rc3;
            Bc[1].d[2] = h0 ? rc2 : od[6];  Bc[1].d[3] = h0 ? rc3 : od[7];
        }

        // ---- layer 2: two chained K=16 MFMAs ----
        D = __builtin_amdgcn_mfma_f32_32x32x16_bf16(w2f[0].b, Bc[0].b, z16, 0, 0, 0);
        D = __builtin_amdgcn_mfma_f32_32x32x16_bf16(w2f[1].b, Bc[1].b, D,   0, 0, 0);

        #pragma unroll
        for (int d = 0; d < 8; ++d) {
            const int r0 = 4 * (d >> 1) + 2 * (d & 1);
            od[d] = pk2(lrelu(D[r0]     + up_lo(b2d[d])),
                        lrelu(D[r0 + 1] + up_hi(b2d[d])));
        }

        // ---- half-exchange #2 ----
        {
            unsigned rc0 = __shfl_xor(h0 ? od[2] : od[0], 32, 64);
            unsigned rc1 = __shfl_xor(h0 ? od[3] : od[1], 32, 64);
            unsigned rc2 = __shfl_xor(h0 ? od[6] : od[4], 32, 64);
            unsigned rc3 = __shfl_xor(h0 ? od[7] : od[5], 32, 64);
            Bc[0].d[0] = h0 ? od[0] : rc0;  Bc[0].d[1] = h0 ? od[1] : rc1;
            Bc[0].d[2] = h0 ? rc0 : od[2];  Bc[0].d[3] = h0 ? rc1 : od[3];
            Bc[1].d[0] = h0 ? od[4] : rc2;  Bc[1].d[1] = h0 ? od[5] : rc3;
            Bc[1].d[2] = h0 ? rc2 : od[6];  Bc[1].d[3] = h0 ? rc3 : od[7];
        }

        // ---- layer 3 ----
        D = __builtin_amdgcn_mfma_f32_32x32x16_bf16(w3f[0].b, Bc[0].b, z16, 0, 0, 0);
        D = __builtin_amdgcn_mfma_f32_32x32x16_bf16(w3f[1].b, Bc[1].b, D,   0, 0, 0);

        // ---- layer 4: bias + lrelu + packed dot2 over this lane's 16 rows ----
        float dot = 0.0f;
        #pragma unroll
        for (int d = 0; d < 8; ++d) {
            const int r0 = 4 * (d >> 1) + 2 * (d & 1);
            const unsigned pd = pk2(lrelu(D[r0]     + up_lo(b3d[d])),
                                    lrelu(D[r0 + 1] + up_hi(b3d[d])));
            dot = dot2bf(w4d[d], pd, dot);
        }
        dot += __shfl_xor(dot, 32, 64);

        if (lane < 32) {
            const float e2x = __expf(2.0f * (dot + b4m));
            const float nn = (1.0f - 2.0f / (e2x + 1.0f)) * NN_RATIO_C;
            const float kk = k0 + k1 * a;
            red_k[w][row]  = kk * ms * ms;
            red_bf[w][row] = (kk * (l0 + l1 * a - fabsf(l)) + k1 * l1 * a * a * nn) * ms;
        }
    }

    __syncthreads();

    if (tid < 64) {
        float Ksum = 0.0f, BFsum = 0.0f;
        #pragma unroll
        for (int mm = 0; mm < 8; ++mm) {
            Ksum  += red_k[mm][tid];
            BFsum += red_bf[mm][tid];
        }

        const int b = rowbase + tid;
        const float2 ssv = *(const float2*)&SS[2 * b];
        const float s0 = ssv.x, s1 = ssv.y;
        const float I  = Ivec[0];
        const float bv = Bv[0];
        const float kv = Kv[0];
        const float inv_I = 1.0f / I;

        const float A10 = -(Ksum + kv) * inv_I;
        const float Dd  = 2.0f * sqrtf(Ksum * I);
        const float A11 = -(Dd + bv) * inv_I;
        const float B10 = BFsum * inv_I;

        // Reduced 3x3 expm (verified R1-R8)
        const float m01 = DT_C;
        const float m10 = A10 * DT_C, m11 = A11 * DT_C, m12 = B10 * DT_C;

        float p00 = 0.0f, p01 = m01, p02 = 0.0f;
        float p10 = m10,  p11 = m11, p12 = m12;
        float t00 = p00, t01 = p01, t02 = p02;
        float t10 = p10, t11 = p11, t12 = p12;
        #pragma unroll
        for (int k = 2; k <= 16; ++k) {
            float inv = 1.0f / (float)k;
            float q00 = (p01 * m10) * inv;
            float q01 = (p00 * m01 + p01 * m11) * inv;
            float q02 = (p01 * m12) * inv;
            float q10 = (p11 * m10) * inv;
            float q11 = (p10 * m01 + p11 * m11) * inv;
            float q12 = (p11 * m12) * inv;
            p00 = q00; p01 = q01; p02 = q02;
            p10 = q10; p11 = q11; p12 = q12;
            t00 += p00; t01 += p01; t02 += p02;
            t10 += p10; t11 += p11; t12 += p12;
        }
        const float E00 = 1.0f + t00, E01 = t01, c0 = t02;
        const float E10 = t10,        E11 = 1.0f + t11, c1 = t12;

        const float o0 = E00 * s0 + E01 * s1 + c0;
        const float o1 = E10 * s0 + E11 * s1 + c1;

        out[b] = o0;                               // output 0: SSout[:,0:1]
        float2 o12; o12.x = o0; o12.y = o1;        // output 1: SSout[:,:,0]
        *(float2*)&out[BATCH + 2 * b] = o12;
    }
}

extern "C" void kernel_launch(void* const* d_in, const int* in_sizes, int n_in,
                              void* d_out, int out_size, void* d_ws, size_t ws_size,
                              hipStream_t stream) {
    const float* SS     = (const float*)d_in[0];
    const float* Alphas = (const float*)d_in[1];
    const float* K0s    = (const float*)d_in[2];
    const float* K1s    = (const float*)d_in[3];
    const float* L0s    = (const float*)d_in[4];
    const float* L1s    = (const float*)d_in[5];
    const float* Ms     = (const float*)d_in[6];
    const float* I      = (const float*)d_in[7];
    const float* Bv     = (const float*)d_in[8];
    const float* Kv     = (const float*)d_in[9];
    const float* W1     = (const float*)d_in[10];
    const float* b1     = (const float*)d_in[11];
    const float* W2     = (const float*)d_in[12];
    const float* b2     = (const float*)d_in[13];
    const float* W3     = (const float*)d_in[14];
    const float* b3     = (const float*)d_in[15];
    const float* W4     = (const float*)d_in[16];
    const float* b4     = (const float*)d_in[17];
    float* out = (float*)d_out;

    joint_kernel<<<BATCH / 64, 512, 0, stream>>>(
        SS, Alphas, K0s, K1s, L0s, L1s, Ms, I, Bv, Kv,
        W1, b1, W2, b2, W3, b3, W4, b4, out);
}